// Round 2
// baseline (976.408 us; speedup 1.0000x reference)
//
#include <hip/hip_runtime.h>

typedef __attribute__((ext_vector_type(8))) short short8;
typedef __attribute__((ext_vector_type(4))) float f32x4;

__device__ __forceinline__ short f2bf(float f) {
  unsigned u = __builtin_bit_cast(unsigned, f);
  u = (u + 0x7fffu + ((u >> 16) & 1u)) >> 16;  // RNE
  return (short)u;
}

// ---------------------------------------------------------------------------
// Prep: bias gather -> bias4[h][r][lm][nt] (float4-loadable in MFMA C-layout);
// optional mask permute -> mask4[wi][r][lm][nt]; weight pre-transpose+swizzle
// into MFMA B-fragment-linear bf16: frag[lane][j] = W[ks*32+(lane>>4)*8+j][nt*16+(lane&15)]
// ---------------------------------------------------------------------------
__global__ void prep_kernel(const float* __restrict__ qkv_w,
                            const float* __restrict__ proj_w,
                            const float* __restrict__ rpb,
                            const int* __restrict__ rel_index,
                            const float* __restrict__ mask,
                            float* __restrict__ bias4,
                            short* __restrict__ wsq,
                            short* __restrict__ wsp,
                            float* __restrict__ mask4, int do_mask) {
  int idx = blockIdx.x * 256 + threadIdx.x;
  if (idx < 24576) {  // 6*64*16*4 bias gather, permuted
    int nt = idx & 3, lm = (idx >> 2) & 15, r = (idx >> 6) & 63, h = idx >> 12;
    bias4[idx] = rpb[rel_index[r * 64 + nt * 16 + lm] * 6 + h];
  }
  int i2 = idx - 24576;
  if (i2 >= 0 && i2 < 27648) {  // qkv_w frags: 18 nt * 3 ks * 64 lanes * 8 j
    int j = i2 & 7;
    int lane = (i2 >> 3) & 63;
    int frag = i2 >> 9;
    int ks = frag % 3, nt = frag / 3;
    int k = ks * 32 + (lane >> 4) * 8 + j;
    int n = nt * 16 + (lane & 15);
    wsq[i2] = f2bf(qkv_w[k * 288 + n]);
  }
  int i3 = i2 - 27648;
  if (i3 >= 0 && i3 < 9216) {  // proj_w frags: 6 nt * 3 ks * 64 * 8
    int j = i3 & 7;
    int lane = (i3 >> 3) & 63;
    int frag = i3 >> 9;
    int ks = frag % 3, nt = frag / 3;
    int k = ks * 32 + (lane >> 4) * 8 + j;
    int n = nt * 16 + (lane & 15);
    wsp[i3] = f2bf(proj_w[k * 96 + n]);
  }
  int i4 = i3 - 9216;
  if (do_mask && i4 >= 0 && i4 < 2097152) {  // 512*64*16*4 mask permute
    int nt = i4 & 3, lm = (i4 >> 2) & 15, r = (i4 >> 6) & 63, wi = i4 >> 12;
    mask4[i4] = mask[wi * 4096 + r * 64 + nt * 16 + lm];
  }
}

// ---------------------------------------------------------------------------
// Fused window attention. 1 block/window, 256 thr (4 waves), 3 blocks/CU.
// Only 3 __syncthreads per block: all softmax/concat LDS round-trips are
// wave-local (wave w touches only rows w*16..w*16+15 -> per-wave pcb chunk).
// ---------------------------------------------------------------------------
__global__ __launch_bounds__(256, 3) void winattn_kernel(
    const float* __restrict__ x, const float* __restrict__ mask,
    const float* __restrict__ mask4, int packed,
    const float* __restrict__ qkv_b, const float* __restrict__ proj_b,
    const float* __restrict__ bias4, const short* __restrict__ wsq,
    const short* __restrict__ wsp, float* __restrict__ out) {
  // qk: rows 64, cols 0..95 = q (pre-scaled 0.25), 96..191 = k; stride 200.
  // Reused as float out_s[64][100] for the coalesced store stage.
  __shared__ __align__(16) short qk[64 * 200];     // 25600 B
  __shared__ __align__(16) short vT[96 * 72];      // v^T [d][j], 13824 B
  __shared__ __align__(16) short pcb[4][16 * 104]; // per-wave P / concat, 13312 B

  const int b = blockIdx.x;
  const int t = threadIdx.x;
  const int w = t >> 6;
  const int l = t & 63;
  const int lm = l & 15;
  const int quad = l >> 4;

  // ---- Phase 1: qkv = x @ Wqkv + b ----
  short8 afr[4][3];
#pragma unroll
  for (int mt = 0; mt < 4; ++mt)
#pragma unroll
    for (int ks = 0; ks < 3; ++ks) {
      const float* xp = x + ((size_t)b * 64 + mt * 16 + lm) * 96 + ks * 32 + quad * 8;
      const f32x4 u0 = __builtin_nontemporal_load((const f32x4*)xp);
      const f32x4 u1 = __builtin_nontemporal_load((const f32x4*)(xp + 4));
      short8 a;
      a[0] = f2bf(u0[0]); a[1] = f2bf(u0[1]); a[2] = f2bf(u0[2]); a[3] = f2bf(u0[3]);
      a[4] = f2bf(u1[0]); a[5] = f2bf(u1[1]); a[6] = f2bf(u1[2]); a[7] = f2bf(u1[3]);
      afr[mt][ks] = a;
    }

  const short8* wsq8 = (const short8*)wsq;
  for (int u = w * 9; u < w * 9 + 9; ++u) {  // 36 units = 18 nt x 2 m-halves
    const int nt = u >> 1, mh = (u & 1) * 2;
    short8 bfr[3];
#pragma unroll
    for (int ks = 0; ks < 3; ++ks) bfr[ks] = wsq8[(nt * 3 + ks) * 64 + l];
    const int c = nt * 16 + lm;
    const float bq = qkv_b[c];
    const float sc = (c < 96) ? 0.25f : 1.0f;
#pragma unroll
    for (int mi = 0; mi < 2; ++mi) {
      const int mt = mh + mi;
      f32x4 acc = {bq, bq, bq, bq};
#pragma unroll
      for (int ks = 0; ks < 3; ++ks)
        acc = __builtin_amdgcn_mfma_f32_16x16x32_bf16(afr[mt][ks], bfr[ks], acc, 0, 0, 0);
#pragma unroll
      for (int i = 0; i < 4; ++i) {
        const int r = mt * 16 + quad * 4 + i;
        const short v = f2bf(acc[i] * sc);
        if (c < 192) qk[r * 200 + c] = v;
        else vT[(c - 192) * 72 + r] = v;
      }
    }
  }
  __syncthreads();  // barrier 1: qk/vT produced by all waves

  // ---- Phase 2: per-head attention, no barriers (wave-local round-trips) --
  short8 qa[6];
#pragma unroll
  for (int h = 0; h < 6; ++h) {
    short8 q0 = {0, 0, 0, 0, 0, 0, 0, 0};
    if (quad < 2) q0 = *(const short8*)&qk[(w * 16 + lm) * 200 + h * 16 + quad * 8];
    qa[h] = q0;
  }

  f32x4 oacc[6];
  const int rbase = w * 16 + quad * 4;
  const int wi = b & 511;
  short* pbw = pcb[w];
  const float* maskp = mask + (size_t)wi * 4096;
  for (int h = 0; h < 6; ++h) {
    const f32x4 z4 = {0.f, 0.f, 0.f, 0.f};
    f32x4 lac[4];
#pragma unroll
    for (int nt = 0; nt < 4; ++nt) {
      short8 kb = {0, 0, 0, 0, 0, 0, 0, 0};
      if (quad < 2)
        kb = *(const short8*)&qk[(nt * 16 + lm) * 200 + 96 + h * 16 + quad * 8];
      lac[nt] = __builtin_amdgcn_mfma_f32_16x16x32_bf16(qa[h], kb, z4, 0, 0, 0);
    }
#pragma unroll
    for (int i = 0; i < 4; ++i) {
      const int r = rbase + i;
      const f32x4 bb = *(const f32x4*)&bias4[((h * 64 + r) * 16 + lm) * 4];
      f32x4 mm;
      if (packed) {
        mm = *(const f32x4*)&mask4[(((size_t)wi * 64 + r) * 16 + lm) * 4];
      } else {
        const float* mp = maskp + (r << 6);
        mm[0] = mp[lm]; mm[1] = mp[16 + lm]; mm[2] = mp[32 + lm]; mm[3] = mp[48 + lm];
      }
      float lv[4];
      float mx = -3.0e38f;
#pragma unroll
      for (int nt = 0; nt < 4; ++nt) {
        lv[nt] = lac[nt][i] + bb[nt] + mm[nt];
        mx = fmaxf(mx, lv[nt]);
      }
      mx = fmaxf(mx, __shfl_xor(mx, 1));
      mx = fmaxf(mx, __shfl_xor(mx, 2));
      mx = fmaxf(mx, __shfl_xor(mx, 4));
      mx = fmaxf(mx, __shfl_xor(mx, 8));
      float sm = 0.f;
#pragma unroll
      for (int nt = 0; nt < 4; ++nt) { lv[nt] = __expf(lv[nt] - mx); sm += lv[nt]; }
      sm += __shfl_xor(sm, 1);
      sm += __shfl_xor(sm, 2);
      sm += __shfl_xor(sm, 4);
      sm += __shfl_xor(sm, 8);
      const float inv = 1.0f / sm;
#pragma unroll
      for (int nt = 0; nt < 4; ++nt)
        pbw[(quad * 4 + i) * 104 + nt * 16 + lm] = f2bf(lv[nt] * inv);
    }
    // PV (wave-local read of pbw; in-order DS pipe, no barrier needed)
    f32x4 oa = {0.f, 0.f, 0.f, 0.f};
#pragma unroll
    for (int ks = 0; ks < 2; ++ks) {
      const short8 pa = *(const short8*)&pbw[lm * 104 + ks * 32 + quad * 8];
      const short8 vb = *(const short8*)&vT[(h * 16 + lm) * 72 + ks * 32 + quad * 8];
      oa = __builtin_amdgcn_mfma_f32_16x16x32_bf16(pa, vb, oa, 0, 0, 0);
    }
    oacc[h] = oa;
  }

  // ---- Phase 3: out = concat(O) @ proj_w + b (concat via wave-local pbw) --
#pragma unroll
  for (int h = 0; h < 6; ++h)
#pragma unroll
    for (int i = 0; i < 4; ++i)
      pbw[(quad * 4 + i) * 104 + h * 16 + lm] = f2bf(oacc[h][i]);

  short8 ca[3];
#pragma unroll
  for (int ks = 0; ks < 3; ++ks)
    ca[ks] = *(const short8*)&pbw[lm * 104 + ks * 32 + quad * 8];

  const short8* wsp8 = (const short8*)wsp;
  float accs[6][4];
#pragma unroll
  for (int nt = 0; nt < 6; ++nt) {
    short8 pw[3];
#pragma unroll
    for (int ks = 0; ks < 3; ++ks) pw[ks] = wsp8[(nt * 3 + ks) * 64 + l];
    const float bp = proj_b[nt * 16 + lm];
    f32x4 acc = {bp, bp, bp, bp};
#pragma unroll
    for (int ks = 0; ks < 3; ++ks)
      acc = __builtin_amdgcn_mfma_f32_16x16x32_bf16(ca[ks], pw[ks], acc, 0, 0, 0);
#pragma unroll
    for (int i = 0; i < 4; ++i) accs[nt][i] = acc[i];
  }

  __syncthreads();  // barrier 2: all phase-2 qk/vT reads complete
  float* out_s = (float*)qk;  // 64 x 100 f32 = 25600 B, fits exactly
#pragma unroll
  for (int nt = 0; nt < 6; ++nt)
#pragma unroll
    for (int i = 0; i < 4; ++i)
      out_s[(rbase + i) * 100 + nt * 16 + lm] = accs[nt][i];
  __syncthreads();  // barrier 3: staging visible

  float* outp = out + (size_t)b * 6144;
#pragma unroll
  for (int i = 0; i < 6; ++i) {
    const int idx = i * 256 + t;  // 1536 float4s
    const int row = idx / 24, col = idx % 24;
    const f32x4 vv = *(const f32x4*)&out_s[row * 100 + col * 4];
    __builtin_nontemporal_store(vv, (f32x4*)&outp[row * 96 + col * 4]);
  }
}

extern "C" void kernel_launch(void* const* d_in, const int* in_sizes, int n_in,
                              void* d_out, int out_size, void* d_ws, size_t ws_size,
                              hipStream_t stream) {
  const float* x      = (const float*)d_in[0];
  const float* mask   = (const float*)d_in[1];
  const float* qkv_w  = (const float*)d_in[2];
  const float* qkv_b  = (const float*)d_in[3];
  const float* proj_w = (const float*)d_in[4];
  const float* proj_b = (const float*)d_in[5];
  const float* rpb    = (const float*)d_in[6];
  const int*   rel    = (const int*)d_in[7];

  float* bias4 = (float*)d_ws;                           // 98304 B
  short* wsq   = (short*)((char*)d_ws + 98304);          // 55296 B
  short* wsp   = (short*)((char*)d_ws + 153600);         // 18432 B
  float* mask4 = (float*)((char*)d_ws + 172032);         // 8388608 B
  const int packed = (ws_size >= (size_t)172032 + 8388608) ? 1 : 0;

  const int prep_elems = 61440 + (packed ? 2097152 : 0);
  hipLaunchKernelGGL(prep_kernel, dim3((prep_elems + 255) / 256), dim3(256), 0,
                     stream, qkv_w, proj_w, rpb, rel, mask, bias4, wsq, wsp,
                     mask4, packed);
  hipLaunchKernelGGL(winattn_kernel, dim3(8192), dim3(256), 0, stream,
                     x, mask, mask4, packed, qkv_b, proj_b, bias4, wsq, wsp,
                     (float*)d_out);
}